// Round 1
// baseline (95.751 us; speedup 1.0000x reference)
//
#include <hip/hip_runtime.h>
#include <hip/hip_bf16.h>
#include <math.h>

#define B_SZ   256
#define T_SZ   50
#define N_OBS  8192
#define N_KC   50

// K1: recover assign[i] = argmax of one-hot row A[i,:], and kc_probs = sigmoid(kc_logits)
__global__ void k_assign(const float* __restrict__ A,
                         const float* __restrict__ kc_logits,
                         int* __restrict__ assign,
                         float* __restrict__ kc_probs) {
    int i = blockIdx.x * blockDim.x + threadIdx.x;
    if (i < N_OBS) {
        const float* row = A + (long)i * N_KC;
        int a = 0;
        #pragma unroll
        for (int j = 0; j < N_KC; ++j) {
            if (row[j] > 0.5f) a = j;
        }
        assign[i] = a;
    }
    if (blockIdx.x == 0 && threadIdx.x < N_KC * 5) {
        float x = kc_logits[threadIdx.x];
        kc_probs[threadIdx.x] = 1.0f / (1.0f + expf(-x));
    }
}

// K2: one wave (64 threads) per batch element.
// Lane k < 50 holds per-KC state in a register; serial recurrence via __shfl.
__global__ void __launch_bounds__(64) k_scan(
        const int*   __restrict__ prev_kc,
        const int*   __restrict__ curr_kc,
        const float* __restrict__ prev_corr,
        const int*   __restrict__ assign,
        const float* __restrict__ kc_probs,
        float* __restrict__ probs_out,    // [B][T]
        float* __restrict__ state_out) {  // [B][N_OBS]
    const int b    = blockIdx.x;
    const int lane = threadIdx.x;  // 0..63

    __shared__ float s_probs[N_KC * 5 + 6];
    for (int i = lane; i < N_KC * 5; i += 64) s_probs[i] = kc_probs[i];
    __syncthreads();

    // Per-step constants: lane t (t < T) holds the values for timestep t.
    int   ka = 0, kc = 0;
    float po0 = 0.f, po1 = 0.f, pl = 0.f, pf = 0.f, cp2 = 0.f, cp3 = 0.f;
    if (lane < T_SZ) {
        int   pk   = prev_kc[b * T_SZ + lane];
        int   ck   = curr_kc[b * T_SZ + lane];
        float corr = prev_corr[b * T_SZ + lane];
        ka = assign[pk];
        kc = assign[ck];
        float pp0 = s_probs[ka * 5 + 0];
        float pp1 = s_probs[ka * 5 + 1];
        float pp2 = s_probs[ka * 5 + 2];
        float pp3 = s_probs[ka * 5 + 3];
        // prev_corr is exactly 0.0 or 1.0, so pow() reduces to a select.
        bool c = corr > 0.5f;
        po0 = c ? pp2 : 1.0f - pp2;
        po1 = c ? pp3 : 1.0f - pp3;
        pl  = pp0;
        pf  = pp1;
        cp2 = s_probs[kc * 5 + 2];
        cp3 = s_probs[kc * 5 + 3];
    }

    // Initial per-KC state: lane k holds sigmoid(kc_logits[k,4]).
    float st = (lane < N_KC) ? s_probs[lane * 5 + 4] : 0.0f;

    float pc_mine = 0.0f;

    // t = 0: no state update, just the prediction.
    {
        int   kc0  = __shfl(kc, 0);
        float cs   = __shfl(st, kc0);
        float c2   = __shfl(cp2, 0);
        float c3   = __shfl(cp3, 0);
        float pc   = c2 * (1.0f - cs) + c3 * cs;
        if (lane == 0) pc_mine = pc;
    }

    // t = 1..T-1: the serial recurrence. All broadcast values are wave-uniform.
    for (int t = 1; t < T_SZ; ++t) {
        int   ka_t  = __shfl(ka, t);
        float po0_t = __shfl(po0, t);
        float po1_t = __shfl(po1, t);
        float pl_t  = __shfl(pl, t);
        float pf_t  = __shfl(pf, t);

        float ss    = __shfl(st, ka_t);
        float denom = po0_t * (1.0f - ss) + po1_t * ss;
        float filt  = po1_t * ss / denom;
        float pred  = pl_t * (1.0f - filt) + (1.0f - pf_t) * filt;
        if (lane == ka_t) st = pred;

        int   kc_t = __shfl(kc, t);
        float cs   = __shfl(st, kc_t);
        float c2   = __shfl(cp2, t);
        float c3   = __shfl(cp3, t);
        float pc   = c2 * (1.0f - cs) + c3 * cs;
        if (lane == t) pc_mine = pc;
    }

    if (lane < T_SZ) probs_out[b * T_SZ + lane] = pc_mine;

    // Expand per-KC state to per-observation state for this batch row.
    const long base = (long)b * N_OBS;
    for (int j = lane; j < N_OBS; j += 64) {
        int   aj = assign[j];
        float v  = __shfl(st, aj);
        state_out[base + j] = v;
    }
}

extern "C" void kernel_launch(void* const* d_in, const int* in_sizes, int n_in,
                              void* d_out, int out_size, void* d_ws, size_t ws_size,
                              hipStream_t stream) {
    const int*   prev_kc   = (const int*)  d_in[0];
    const int*   curr_kc   = (const int*)  d_in[1];
    const float* prev_corr = (const float*)d_in[2];
    const float* kc_logits = (const float*)d_in[3];
    const float* A         = (const float*)d_in[4];

    float* probs_out = (float*)d_out;                 // B*T
    float* state_out = (float*)d_out + B_SZ * T_SZ;   // B*N_OBS

    int*   assign   = (int*)d_ws;
    float* kc_probs = (float*)((char*)d_ws + N_OBS * sizeof(int));

    k_assign<<<N_OBS / 256, 256, 0, stream>>>(A, kc_logits, assign, kc_probs);
    k_scan<<<B_SZ, 64, 0, stream>>>(prev_kc, curr_kc, prev_corr,
                                    assign, kc_probs, probs_out, state_out);
}

// Round 2
// 78.511 us; speedup vs baseline: 1.2196x; 1.2196x over previous
//
#include <hip/hip_runtime.h>
#include <hip/hip_bf16.h>
#include <math.h>

#define B_SZ   256
#define T_SZ   50
#define N_OBS  8192
#define N_KC   50

// ---------------------------------------------------------------------------
// K1: assign[i] = column of the single 1.0 in one-hot row A[i,:], plus
//     kc_probs = sigmoid(kc_logits). A is scanned FLAT with float4 so reads
//     are fully coalesced; each one-hot hit produces one scattered store.
// ---------------------------------------------------------------------------
__global__ void __launch_bounds__(256) k_assign(
        const float* __restrict__ A,
        const float* __restrict__ kc_logits,
        int* __restrict__ assign,
        float* __restrict__ kc_probs) {
    const int idx = blockIdx.x * 256 + threadIdx.x;       // float4 index
    // N_OBS*N_KC = 409600 floats = 102400 float4 -> exactly 400 blocks.
    const float4 v = ((const float4*)A)[idx];
    const int e = idx * 4;
    if (v.x > 0.5f) assign[(e + 0) / N_KC] = (e + 0) % N_KC;
    if (v.y > 0.5f) assign[(e + 1) / N_KC] = (e + 1) % N_KC;
    if (v.z > 0.5f) assign[(e + 2) / N_KC] = (e + 2) % N_KC;
    if (v.w > 0.5f) assign[(e + 3) / N_KC] = (e + 3) % N_KC;

    if (blockIdx.x == 0 && threadIdx.x < N_KC * 5) {
        float x = kc_logits[threadIdx.x];
        kc_probs[threadIdx.x] = 1.0f / (1.0f + expf(-x));
    }
}

// ---------------------------------------------------------------------------
// K2: one wave per batch element. Lane k < 50 holds per-KC state in a
//     register; the serial recurrence runs over __shfl broadcasts. Outputs
//     the 50 per-step probs and the tiny per-KC final state (to d_ws).
// ---------------------------------------------------------------------------
__global__ void __launch_bounds__(64) k_scan(
        const int*   __restrict__ prev_kc,
        const int*   __restrict__ curr_kc,
        const float* __restrict__ prev_corr,
        const int*   __restrict__ assign,
        const float* __restrict__ kc_probs,
        float* __restrict__ probs_out,    // [B][T]
        float* __restrict__ kc_state) {   // [B][64]
    const int b    = blockIdx.x;
    const int lane = threadIdx.x;  // 0..63

    __shared__ float s_probs[N_KC * 5 + 6];
    for (int i = lane; i < N_KC * 5; i += 64) s_probs[i] = kc_probs[i];
    __syncthreads();

    // Per-step constants: lane t (t < T) holds the values for timestep t.
    int   ka = 0, kc = 0;
    float po0 = 0.f, po1 = 0.f, pl = 0.f, pf = 0.f, cp2 = 0.f, cp3 = 0.f;
    if (lane < T_SZ) {
        int   pk   = prev_kc[b * T_SZ + lane];
        int   ck   = curr_kc[b * T_SZ + lane];
        float corr = prev_corr[b * T_SZ + lane];
        ka = assign[pk];
        kc = assign[ck];
        float pp0 = s_probs[ka * 5 + 0];
        float pp1 = s_probs[ka * 5 + 1];
        float pp2 = s_probs[ka * 5 + 2];
        float pp3 = s_probs[ka * 5 + 3];
        // prev_corr is exactly 0.0 or 1.0 -> pow() reduces to a select.
        bool c = corr > 0.5f;
        po0 = c ? pp2 : 1.0f - pp2;
        po1 = c ? pp3 : 1.0f - pp3;
        pl  = pp0;
        pf  = pp1;
        cp2 = s_probs[kc * 5 + 2];
        cp3 = s_probs[kc * 5 + 3];
    }

    // Initial per-KC state: lane k holds sigmoid(kc_logits[k,4]).
    float st = (lane < N_KC) ? s_probs[lane * 5 + 4] : 0.0f;

    float pc_mine = 0.0f;

    // t = 0: prediction only, no state update.
    {
        int   kc0 = __shfl(kc, 0);
        float cs  = __shfl(st, kc0);
        float c2  = __shfl(cp2, 0);
        float c3  = __shfl(cp3, 0);
        float pc  = c2 * (1.0f - cs) + c3 * cs;
        if (lane == 0) pc_mine = pc;
    }

    // t = 1..T-1: serial recurrence; all broadcasts are wave-uniform.
    for (int t = 1; t < T_SZ; ++t) {
        int   ka_t  = __shfl(ka, t);
        float po0_t = __shfl(po0, t);
        float po1_t = __shfl(po1, t);
        float pl_t  = __shfl(pl, t);
        float pf_t  = __shfl(pf, t);

        float ss    = __shfl(st, ka_t);
        float denom = po0_t * (1.0f - ss) + po1_t * ss;
        float filt  = po1_t * ss / denom;
        float pred  = pl_t * (1.0f - filt) + (1.0f - pf_t) * filt;
        if (lane == ka_t) st = pred;

        int   kc_t = __shfl(kc, t);
        float cs   = __shfl(st, kc_t);
        float c2   = __shfl(cp2, t);
        float c3   = __shfl(cp3, t);
        float pc   = c2 * (1.0f - cs) + c3 * cs;
        if (lane == t) pc_mine = pc;
    }

    if (lane < T_SZ) probs_out[b * T_SZ + lane] = pc_mine;
    kc_state[b * 64 + lane] = st;   // lanes >= 50 store unused zeros
}

// ---------------------------------------------------------------------------
// K3: expand per-KC state to per-observation state.
//     state_out[b][j] = kc_state[b][assign[j]]. One float4 per thread,
//     grid (8 chunks, 256 batches) x 256 threads = 2048 blocks.
// ---------------------------------------------------------------------------
__global__ void __launch_bounds__(256) k_expand(
        const int*   __restrict__ assign,
        const float* __restrict__ kc_state,
        float* __restrict__ state_out) {
    const int b   = blockIdx.y;
    const int tid = threadIdx.x;

    __shared__ float s_state[N_KC];
    if (tid < N_KC) s_state[tid] = kc_state[b * 64 + tid];
    __syncthreads();

    const int idx = blockIdx.x * 256 + tid;          // float4 index in row, 0..2047
    const int4 a4 = ((const int4*)assign)[idx];
    float4 v;
    v.x = s_state[a4.x];
    v.y = s_state[a4.y];
    v.z = s_state[a4.z];
    v.w = s_state[a4.w];
    ((float4*)state_out)[(long)b * (N_OBS / 4) + idx] = v;
}

extern "C" void kernel_launch(void* const* d_in, const int* in_sizes, int n_in,
                              void* d_out, int out_size, void* d_ws, size_t ws_size,
                              hipStream_t stream) {
    const int*   prev_kc   = (const int*)  d_in[0];
    const int*   curr_kc   = (const int*)  d_in[1];
    const float* prev_corr = (const float*)d_in[2];
    const float* kc_logits = (const float*)d_in[3];
    const float* A         = (const float*)d_in[4];

    float* probs_out = (float*)d_out;                 // B*T
    float* state_out = (float*)d_out + B_SZ * T_SZ;   // B*N_OBS

    int*   assign   = (int*)d_ws;                                       // 32 KB
    float* kc_probs = (float*)((char*)d_ws + N_OBS * sizeof(int));      // 1 KB
    float* kc_state = (float*)((char*)d_ws + N_OBS * sizeof(int) + 1024); // 64 KB

    k_assign<<<(N_OBS * N_KC / 4) / 256, 256, 0, stream>>>(A, kc_logits, assign, kc_probs);
    k_scan<<<B_SZ, 64, 0, stream>>>(prev_kc, curr_kc, prev_corr,
                                    assign, kc_probs, probs_out, kc_state);
    k_expand<<<dim3(N_OBS / 4 / 256, B_SZ), 256, 0, stream>>>(assign, kc_state, state_out);
}